// Round 8
// baseline (102.366 us; speedup 1.0000x reference)
//
#include <hip/hip_runtime.h>

#define B_   16
#define NK_  256
#define NQ_  256
#define DK_  256
#define H_   128
#define DV_  256

// 2*log2(e): features prescaled so exp2(C2X*x) = e^{2x}
#define C2X 2.8853900817779268f
// log2(e) for softmax exp
#define L2E 1.4426950408889634f
#define MASKV -1.0e5f

typedef float f4 __attribute__((ext_vector_type(4)));

__device__ __forceinline__ float exp2_fast(float x) { return __builtin_amdgcn_exp2f(x); }
__device__ __forceinline__ float rcp_fast(float x)  { return __builtin_amdgcn_rcpf(x); }

// ---------------------------------------------------------------------------
// Kernel A: projections -> EXponentiated features.
// R8: W staged in 32-k chunks (16 KB) -> total LDS 32 KB -> up to 5
// blocks/CU (was 48 KB -> 2/CU). More resident blocks hide the barrier
// drains between W chunks; DS:VALU per-iter ratio unchanged.
//   blocks 0..255   : kfE[b][k][h]      = exp2(C2X * (key  @ Wk))
//   blocks 256..511 : qE4[b][h/4][q][4] = exp2(C2X * (query @ Wq))
// ---------------------------------------------------------------------------
__global__ __launch_bounds__(256) void proj_kernel(
    const float* __restrict__ key, const float* __restrict__ query,
    const float* __restrict__ Wk,  const float* __restrict__ Wq,
    float* __restrict__ kfE, float* __restrict__ qE4)
{
    __shared__ alignas(16) float A_s[16 * 256];   // 16 KB
    __shared__ alignas(16) float W_s[32 * 128];   // 16 KB

    const int blk = blockIdx.x;
    const int tid = threadIdx.x;
    const bool isQ = blk >= 256;
    const int rb = (blk & 255) * 16;              // flat row base (b*256 + row)

    const float* __restrict__ A = isQ ? query : key;
    const float* __restrict__ W = isQ ? Wq : Wk;

    // stage 16 x 256 input rows (coalesced float4, 4 per thread)
    {
        const f4* src = (const f4*)(A + (size_t)rb * DK_);
        f4* dst = (f4*)A_s;
#pragma unroll
        for (int j = 0; j < 4; ++j) dst[tid + 256 * j] = src[tid + 256 * j];
    }

    const int rg2 = (tid >> 5) << 1;              // row base: 2 rows
    const int c4  = (tid & 31) << 2;              // col base: 4 cols

    f4 acc0 = {0.f, 0.f, 0.f, 0.f}, acc1 = acc0;

    for (int kc = 0; kc < DK_; kc += 32) {
        __syncthreads();                          // A_s staged / prev W reads done
        {
            const f4* wsrc = (const f4*)(W + (size_t)kc * H_);
            f4* wdst = (f4*)W_s;
#pragma unroll
            for (int j = 0; j < 4; ++j) wdst[tid + 256 * j] = wsrc[tid + 256 * j];
        }
        __syncthreads();
#pragma unroll 2
        for (int k = 0; k < 32; k += 4) {
            f4 w0 = *(const f4*)(W_s + (k + 0) * H_ + c4);
            f4 w1 = *(const f4*)(W_s + (k + 1) * H_ + c4);
            f4 w2 = *(const f4*)(W_s + (k + 2) * H_ + c4);
            f4 w3 = *(const f4*)(W_s + (k + 3) * H_ + c4);
            f4 a0 = *(const f4*)(A_s + (rg2 + 0) * 256 + kc + k);
            f4 a1 = *(const f4*)(A_s + (rg2 + 1) * 256 + kc + k);
            acc0 += a0[0] * w0; acc1 += a1[0] * w0;
            acc0 += a0[1] * w1; acc1 += a1[1] * w1;
            acc0 += a0[2] * w2; acc1 += a1[2] * w2;
            acc0 += a0[3] * w3; acc1 += a1[3] * w3;
        }
    }

    f4 e0, e1;
#pragma unroll
    for (int cc = 0; cc < 4; ++cc) {
        e0[cc] = exp2_fast(C2X * acc0[cc]);
        e1[cc] = exp2_fast(C2X * acc1[cc]);
    }

    if (!isQ) {
        float* dst = kfE + (size_t)(rb + rg2) * H_ + c4;
        *(f4*)(dst)      = e0;
        *(f4*)(dst + H_) = e1;
    } else {
        const int b  = rb >> 8;
        const int q0 = (rb & 255) + rg2;
        f4* dst = (f4*)qE4 + ((size_t)(b * 32 + (c4 >> 2))) * NQ_ + q0;
        dst[0] = e0;                              // query q0   : 4 h-values
        dst[1] = e1;                              // query q0+1
    }
}

// ---------------------------------------------------------------------------
// Kernel B: fused scores + masked softmax + PV.  (R7 verbatim — best known.)
// 1024 blocks x 256 threads, 4 k-rows/block, all 4096 waves always active.
// Phase 1: wave w -> 2 k-rows {k0+2(w>>1), +1}, chunks j == (w&1) mod 2;
// each eq f4 load feeds 2 rows. Phase 2: in-wave softmax per k-row.
// Phase 3: value-read-once PV with LDS reduce.
// ---------------------------------------------------------------------------
__global__ __launch_bounds__(256) void attn_kernel(
    const float* __restrict__ kfE, const float* __restrict__ qE4,
    const float* __restrict__ value, const int* __restrict__ vlens,
    const float* __restrict__ wv, float* __restrict__ out)
{
    __shared__ alignas(16) float sc_s[4 * 260];    // scores [k][q] (pad 260)
    __shared__ alignas(16) float at4_s[256 * 4];   // attn transposed [q][k]
    __shared__ alignas(16) float red_s[16 * 256];  // phase-3 partials

    const int x    = blockIdx.x;
    const int qu   = x >> 8;                       // dispatch round 0..3
    const int xi   = x & 255;
    const int b    = (xi + (qu << 2)) & 15;        // b rotated for balance
    const int kt   = (xi >> 4) + (qu << 4);        // 0..63
    const int k0   = kt << 2;
    const int tid  = threadIdx.x;
    const int lane = tid & 63;
    const int wu   = __builtin_amdgcn_readfirstlane(tid >> 6);
    const int valid  = vlens[b];
    const int nchunk = (valid + 63) >> 6;          // 1..4

    // sum(wv): uniform addresses -> scalar loads
    float sumwv;
    {
        f4 sw = {0.f, 0.f, 0.f, 0.f};
#pragma unroll
        for (int i = 0; i < 32; ++i) sw += ((const f4*)wv)[i];
        sumwv = (sw[0] + sw[1]) + (sw[2] + sw[3]);
    }

    // ---- Phase 1: wave = (row pair p, chunk parity par).
    {
        const int p   = wu >> 1;
        const int par = wu & 1;
        const int l0  = p << 1;                    // local rows l0, l0+1
        const int nslot = (par < nchunk ? 1 : 0) + (par + 2 < nchunk ? 1 : 0);

        if (nslot) {
            const float* ekp = kfE + ((size_t)(b * NK_ + k0 + l0)) * H_; // uniform
            const f4*    eqA = (const f4*)qE4 + (size_t)b * (32 * NQ_)
                               + ((par << 6) + lane);
            const f4*    eqB = eqA + 128;          // chunk par+2

            float acc[2][2][2];
#pragma unroll
            for (int s = 0; s < 2; ++s)
#pragma unroll
                for (int r = 0; r < 2; ++r) { acc[s][r][0] = 0.f; acc[s][r][1] = 0.f; }

            auto body = [&](int NS) {
#pragma unroll 4
                for (int h4 = 0; h4 < 32; ++h4) {
                    const f4 ekA = *(const f4*)(ekp + (h4 << 2));        // s_load
                    const f4 ekB = *(const f4*)(ekp + H_ + (h4 << 2));   // s_load
                    const f4 w4  = *(const f4*)(wv + (h4 << 2));         // s_load
                    {
                        const f4 e = eqA[(size_t)h4 * NQ_];
                        acc[0][0][0] = fmaf(w4[0], rcp_fast(fmaf(ekA[0], e[0], 1.f)), acc[0][0][0]);
                        acc[0][0][1] = fmaf(w4[1], rcp_fast(fmaf(ekA[1], e[1], 1.f)), acc[0][0][1]);
                        acc[0][0][0] = fmaf(w4[2], rcp_fast(fmaf(ekA[2], e[2], 1.f)), acc[0][0][0]);
                        acc[0][0][1] = fmaf(w4[3], rcp_fast(fmaf(ekA[3], e[3], 1.f)), acc[0][0][1]);
                        acc[0][1][0] = fmaf(w4[0], rcp_fast(fmaf(ekB[0], e[0], 1.f)), acc[0][1][0]);
                        acc[0][1][1] = fmaf(w4[1], rcp_fast(fmaf(ekB[1], e[1], 1.f)), acc[0][1][1]);
                        acc[0][1][0] = fmaf(w4[2], rcp_fast(fmaf(ekB[2], e[2], 1.f)), acc[0][1][0]);
                        acc[0][1][1] = fmaf(w4[3], rcp_fast(fmaf(ekB[3], e[3], 1.f)), acc[0][1][1]);
                    }
                    if (NS == 2) {
                        const f4 e = eqB[(size_t)h4 * NQ_];
                        acc[1][0][0] = fmaf(w4[0], rcp_fast(fmaf(ekA[0], e[0], 1.f)), acc[1][0][0]);
                        acc[1][0][1] = fmaf(w4[1], rcp_fast(fmaf(ekA[1], e[1], 1.f)), acc[1][0][1]);
                        acc[1][0][0] = fmaf(w4[2], rcp_fast(fmaf(ekA[2], e[2], 1.f)), acc[1][0][0]);
                        acc[1][0][1] = fmaf(w4[3], rcp_fast(fmaf(ekA[3], e[3], 1.f)), acc[1][0][1]);
                        acc[1][1][0] = fmaf(w4[0], rcp_fast(fmaf(ekB[0], e[0], 1.f)), acc[1][1][0]);
                        acc[1][1][1] = fmaf(w4[1], rcp_fast(fmaf(ekB[1], e[1], 1.f)), acc[1][1][1]);
                        acc[1][1][0] = fmaf(w4[2], rcp_fast(fmaf(ekB[2], e[2], 1.f)), acc[1][1][0]);
                        acc[1][1][1] = fmaf(w4[3], rcp_fast(fmaf(ekB[3], e[3], 1.f)), acc[1][1][1]);
                    }
                }
            };
            if (nslot == 1) body(1); else body(2);

#pragma unroll
            for (int s = 0; s < 2; ++s) {
                if (s < nslot) {
                    const int q = (((par + (s << 1))) << 6) + lane;
                    sc_s[(l0 + 0) * 260 + q] = sumwv - 2.f * (acc[s][0][0] + acc[s][0][1]);
                    sc_s[(l0 + 1) * 260 + q] = sumwv - 2.f * (acc[s][1][0] + acc[s][1][1]);
                }
            }
        }
    }
    __syncthreads();

    // ---- Phase 2: in-wave masked softmax, wave wu -> k-row wu.
    {
        const float* row = sc_s + wu * 260;
        float s[4];
        float m = MASKV;
#pragma unroll
        for (int j = 0; j < 4; ++j) {
            const int q = (j << 6) + lane;
            s[j] = (q < valid) ? row[q] : MASKV;
            m = fmaxf(m, s[j]);
        }
#pragma unroll
        for (int off = 32; off >= 1; off >>= 1)
            m = fmaxf(m, __shfl_xor(m, off, 64));
        float ssum = 0.f;
#pragma unroll
        for (int j = 0; j < 4; ++j) {
            s[j] = exp2_fast(L2E * (s[j] - m));   // masked -> 0
            ssum += s[j];
        }
#pragma unroll
        for (int off = 32; off >= 1; off >>= 1)
            ssum += __shfl_xor(ssum, off, 64);
        const float inv = rcp_fast(ssum);
#pragma unroll
        for (int j = 0; j < 4; ++j)
            at4_s[(((j << 6) + lane) << 2) + wu] = s[j] * inv;
    }
    __syncthreads();

    // ---- Phase 3: out[b][k0+k][d] = sum_q attn[q][k] * value[b][q][d]
    {
        const int rq = tid >> 6;
        const int d4 = lane << 2;
        const float* vb = value + (size_t)b * (NQ_ * DV_) + d4;
        f4 o0 = {0.f,0.f,0.f,0.f}, o1 = o0, o2 = o0, o3 = o0;
#pragma unroll 4
        for (int q = rq; q < valid; q += 4) {
            f4 v  = *(const f4*)(vb + (size_t)q * DV_);
            f4 a4 = *(const f4*)(at4_s + (q << 2));   // uniform b128 broadcast
            o0 += a4[0] * v;
            o1 += a4[1] * v;
            o2 += a4[2] * v;
            o3 += a4[3] * v;
        }
        float* rs = red_s + (rq << 10) + d4;          // red_s[rq*4+k][256]
        *(f4*)(rs + 0)    = o0;
        *(f4*)(rs + 256)  = o1;
        *(f4*)(rs + 512)  = o2;
        *(f4*)(rs + 768)  = o3;
    }
    __syncthreads();

    // cross-wave reduce + store
    {
        const int k  = tid >> 6;
        const int d4 = lane << 2;
        const float* rs = red_s + (k << 8) + d4;
        f4 o = *(const f4*)(rs) + *(const f4*)(rs + 1024)
             + *(const f4*)(rs + 2048) + *(const f4*)(rs + 3072);
        *(f4*)(out + ((size_t)(b * NK_ + k0 + k)) * DV_ + d4) = o;
    }
}

// ---------------------------------------------------------------------------
extern "C" void kernel_launch(void* const* d_in, const int* in_sizes, int n_in,
                              void* d_out, int out_size, void* d_ws, size_t ws_size,
                              hipStream_t stream)
{
    const float* key   = (const float*)d_in[0];
    const float* query = (const float*)d_in[1];
    const float* value = (const float*)d_in[2];
    const int*   vlens = (const int*)  d_in[3];
    const float* Wk    = (const float*)d_in[4];
    const float* Wq    = (const float*)d_in[5];
    const float* wv    = (const float*)d_in[6];
    float* outp = (float*)d_out;

    float* kfE = (float*)d_ws;                        // [B][NK][H]      2 MB
    float* qE4 = kfE + (size_t)B_ * NK_ * H_;         // [B][H/4][NQ][4] 2 MB

    hipLaunchKernelGGL(proj_kernel, dim3(512), dim3(256), 0, stream,
                       key, query, Wk, Wq, kfE, qE4);
    hipLaunchKernelGGL(attn_kernel, dim3(1024), dim3(256), 0, stream,
                       kfE, qE4, value, vlens, wv, outp);
}